// Round 2
// baseline (1278.640 us; speedup 1.0000x reference)
//
#include <hip/hip_runtime.h>
#include <math.h>

// Problem constants (fixed by setup_inputs): B=4096, D=256, S=256, fp32.
#define BB 4096
#define DD 256
#define SS 256

typedef float f32x4 __attribute__((ext_vector_type(4)));

// Block = 256 threads = 4 waves; each wave handles one batch row.
// Grid = B/4 = 1024 blocks (= 4 blocks/CU on 256 CUs).
//
// Per-wave PHASE ROTATION of the K-loop: every wave streams a 256KB-aligned
// panel of proj; without rotation all ~4096 concurrent waves sit at the same
// offset-within-panel at any instant (panel bases differ only in bits >=18),
// so the low address bits that pick HBM channels/banks are identical
// device-wide -> channel camping (prev measurement: ~835 GB/s = 13% of
// achievable). Rotating each wave's start row by a bijective per-b hash
// spreads instantaneous traffic over the full 256KB phase space. Sum-order
// change is ~1e-6 in fp32, through tanh (Lipschitz 1).
__global__ __launch_bounds__(256, 4) void SFAM_43490838839386_kernel(
    const float* __restrict__ raw_emb,   // [B, D]
    const float* __restrict__ proj,      // [B, D, S]
    const float* __restrict__ noise,     // [B, D]
    float* __restrict__ out)             // [B, S]
{
    __shared__ float fbuf[4 * DD];  // one 256-float f-vector per wave

    const int wave = threadIdx.x >> 6;
    const int lane = threadIdx.x & 63;
    const int b = blockIdx.x * 4 + wave;

    // ---- Phase 1: f = clip(tanh(x)/||tanh(x)|| + 0.01*noise, -1.5, 1.5) ----
    const f32x4 r = *(const f32x4*)(raw_emb + (size_t)b * DD + 4 * lane);
    f32x4 t;
    t.x = tanhf(r.x); t.y = tanhf(r.y); t.z = tanhf(r.z); t.w = tanhf(r.w);

    float ss = t.x * t.x + t.y * t.y + t.z * t.z + t.w * t.w;
#pragma unroll
    for (int off = 32; off >= 1; off >>= 1)
        ss += __shfl_xor(ss, off, 64);

    const float inv = 1.0f / fmaxf(sqrtf(ss), 1e-12f);

    const f32x4 nz = *(const f32x4*)(noise + (size_t)b * DD + 4 * lane);
    f32x4 f;
    f.x = fminf(fmaxf(t.x * inv + 0.01f * nz.x, -1.5f), 1.5f);
    f.y = fminf(fmaxf(t.y * inv + 0.01f * nz.y, -1.5f), 1.5f);
    f.z = fminf(fmaxf(t.z * inv + 0.01f * nz.z, -1.5f), 1.5f);
    f.w = fminf(fmaxf(t.w * inv + 0.01f * nz.w, -1.5f), 1.5f);

    *(f32x4*)(fbuf + wave * DD + 4 * lane) = f;
    __syncthreads();  // once per kernel; makes the LDS RAW explicit

    // ---- Phase 2: out[b, j] = tanh(sum_i f[i] * P[b, i, j]) ----
    // Lane owns columns [4*lane, 4*lane+4). Loads are lane-contiguous 16B
    // (1KB per wave instruction, fully coalesced).
    const float* __restrict__ Pb = proj + (size_t)b * DD * SS;
    const int c = 4 * lane;
    const float* fw = fbuf + wave * DD;

    f32x4 acc = {0.0f, 0.0f, 0.0f, 0.0f};

    // Bijective per-wave phase in [0,64): rotates the start row in 4-row
    // (4KB) steps. readfirstlane -> scalar loop bounds (ph is wave-uniform).
    const int ph = __builtin_amdgcn_readfirstlane((b * 37) & 63);

#define DOT_STEP(kk)                                                                              \
    {                                                                                             \
        const int i = (kk) << 2;                                                                  \
        const f32x4 fv = *(const f32x4*)(fw + i); /* same-addr LDS broadcast */                   \
        const f32x4 p0 = __builtin_nontemporal_load((const f32x4*)(Pb + (size_t)(i + 0) * SS + c)); \
        const f32x4 p1 = __builtin_nontemporal_load((const f32x4*)(Pb + (size_t)(i + 1) * SS + c)); \
        const f32x4 p2 = __builtin_nontemporal_load((const f32x4*)(Pb + (size_t)(i + 2) * SS + c)); \
        const f32x4 p3 = __builtin_nontemporal_load((const f32x4*)(Pb + (size_t)(i + 3) * SS + c)); \
        acc += fv.x * p0;                                                                         \
        acc += fv.y * p1;                                                                         \
        acc += fv.z * p2;                                                                         \
        acc += fv.w * p3;                                                                         \
    }

    // Two affine sub-loops (k in [ph,64) then [0,ph)) instead of (k+ph)&63
    // so addressing stays compile-time affine. unroll 4 -> 16 outstanding
    // dwordx4 loads per wave (64 VGPR of load data; fits the 128-VGPR
    // budget from __launch_bounds__(256,4)).
#pragma unroll 4
    for (int k = ph; k < 64; ++k) DOT_STEP(k)
#pragma unroll 4
    for (int k = 0; k < ph; ++k) DOT_STEP(k)

#undef DOT_STEP

    f32x4 o;
    o.x = tanhf(acc.x); o.y = tanhf(acc.y); o.z = tanhf(acc.z); o.w = tanhf(acc.w);
    *(f32x4*)(out + (size_t)b * SS + c) = o;
}

extern "C" void kernel_launch(void* const* d_in, const int* in_sizes, int n_in,
                              void* d_out, int out_size, void* d_ws, size_t ws_size,
                              hipStream_t stream) {
    const float* raw_emb = (const float*)d_in[0];
    const float* proj    = (const float*)d_in[1];
    const float* noise   = (const float*)d_in[2];
    float* out = (float*)d_out;

    dim3 grid(BB / 4), block(256);
    SFAM_43490838839386_kernel<<<grid, block, 0, stream>>>(raw_emb, proj, noise, out);
}